// Round 1
// baseline (176.870 us; speedup 1.0000x reference)
//
#include <hip/hip_runtime.h>

// out[b] = sum_h [ dot(x1_bh, W1_h) + b1_h + dot(x2_bh, W2_h)
//                  + sum_o x2_bh[o] * dot(W3_h[o,:], x1_bh[:]) ]
// B=16384, HEAD=8, DIM=128.
//
// Layout: block = 512 threads = 8 waves. wave w handles head w for a tile of
// 64 samples (lane = sample). x1 row lives in 128 VGPRs, reused across all
// 128 W3 rows. W3/W1/W2/b1 addresses are wave-uniform (readfirstlane hint) so
// they take the scalar/broadcast path -> no LDS traffic, 1 FMA per MAC.

#define NB 16384
#define NHEAD 8
#define NDIM 128
#define TILE 64

__global__ __launch_bounds__(512, 2) void bilinear_fused_kernel(
    const float* __restrict__ x1, const float* __restrict__ x2,
    const float* __restrict__ W1, const float* __restrict__ b1,
    const float* __restrict__ W2, const float* __restrict__ W3,
    float* __restrict__ out)
{
    const int wave = threadIdx.x >> 6;
    const int lane = threadIdx.x & 63;
    // force wave-uniformity so W1/W2/b1/W3 indexing scalarizes (s_load path)
    const int h = __builtin_amdgcn_readfirstlane(wave);
    const int b = blockIdx.x * TILE + lane;

    const float* __restrict__ x1p = x1 + (size_t)b * (NHEAD * NDIM) + (size_t)h * NDIM;
    const float* __restrict__ x2p = x2 + (size_t)b * (NHEAD * NDIM) + (size_t)h * NDIM;
    const float* __restrict__ w3p = W3 + (size_t)h * NDIM * NDIM;
    const float* __restrict__ w1p = W1 + (size_t)h * NDIM;
    const float* __restrict__ w2p = W2 + (size_t)h * NDIM;

    // ---- load x1 row into registers (fully unrolled -> stays in VGPRs) ----
    float xv[NDIM];
#pragma unroll
    for (int i = 0; i < NDIM / 4; ++i) {
        const float4 v = reinterpret_cast<const float4*>(x1p)[i];
        xv[4 * i + 0] = v.x; xv[4 * i + 1] = v.y;
        xv[4 * i + 2] = v.z; xv[4 * i + 3] = v.w;
    }

    // ---- t1 = dot(x1, W1_h) + b1_h ----
    float t1a = 0.f, t1b = 0.f, t1c = 0.f, t1d = 0.f;
#pragma unroll
    for (int i = 0; i < NDIM / 4; ++i) {
        const float4 w = reinterpret_cast<const float4*>(w1p)[i];
        t1a += w.x * xv[4 * i + 0];
        t1b += w.y * xv[4 * i + 1];
        t1c += w.z * xv[4 * i + 2];
        t1d += w.w * xv[4 * i + 3];
    }
    float acc = (t1a + t1b) + (t1c + t1d) + b1[h];

    // ---- main loop: t2 and t3, streaming x2 and W3 rows ----
    float t3 = 0.f;
    for (int ob = 0; ob < NDIM / 4; ++ob) {          // 32 o-blocks of 4 rows
        const float4 x2v = reinterpret_cast<const float4*>(x2p)[ob];
        const float4 w2v = reinterpret_cast<const float4*>(w2p)[ob];
        acc += w2v.x * x2v.x + w2v.y * x2v.y + w2v.z * x2v.z + w2v.w * x2v.w;

#pragma unroll
        for (int j = 0; j < 4; ++j) {
            const int o = 4 * ob + j;
            const float* __restrict__ row = w3p + (size_t)o * NDIM;
            float a0 = 0.f, a1 = 0.f, a2 = 0.f, a3 = 0.f;  // 4-way ILP
#pragma unroll
            for (int i = 0; i < NDIM / 4; ++i) {
                const float4 w = reinterpret_cast<const float4*>(row)[i];
                a0 += w.x * xv[4 * i + 0];
                a1 += w.y * xv[4 * i + 1];
                a2 += w.z * xv[4 * i + 2];
                a3 += w.w * xv[4 * i + 3];
            }
            const float s = (a0 + a1) + (a2 + a3);
            const float x2s = (j == 0) ? x2v.x : (j == 1) ? x2v.y
                            : (j == 2) ? x2v.z : x2v.w;
            t3 += x2s * s;
        }
    }
    acc += t3;

    // ---- cross-head reduction in LDS, wave 0 writes coalesced output ----
    __shared__ float part[NHEAD][TILE];
    part[wave][lane] = acc;
    __syncthreads();
    if (wave == 0) {
        float s = 0.f;
#pragma unroll
        for (int w = 0; w < NHEAD; ++w) s += part[w][lane];
        out[b] = s;
    }
}

extern "C" void kernel_launch(void* const* d_in, const int* in_sizes, int n_in,
                              void* d_out, int out_size, void* d_ws, size_t ws_size,
                              hipStream_t stream) {
    const float* x1 = (const float*)d_in[0];
    const float* x2 = (const float*)d_in[1];
    const float* W1 = (const float*)d_in[2];
    const float* b1 = (const float*)d_in[3];
    const float* W2 = (const float*)d_in[4];
    const float* W3 = (const float*)d_in[5];
    float* out = (float*)d_out;

    dim3 grid(NB / TILE);   // 256 blocks -> 1 per CU, 2048 waves
    dim3 block(512);
    bilinear_fused_kernel<<<grid, block, 0, stream>>>(x1, x2, W1, b1, W2, W3, out);
}

// Round 2
// 123.694 us; speedup vs baseline: 1.4299x; 1.4299x over previous
//
#include <hip/hip_runtime.h>

// out[b] = sum_h [ dot(x1_bh,W1_h) + b1_h + dot(x2_bh,W2_h)
//                  + sum_o x2_bh[o] * dot(W3_h[o,:], x1_bh) ]
// B=16384, HEAD=8, DIM=128.
//
// Design: W3 lives in VGPRs (persistent per block), samples stream through.
// Block = 1024 thr = 16 waves = 4 heads x 4 waves/head. Wave (h_local,q) owns
// rows o in [q*32,q*32+32); lane: ol=lane&31 -> row, ch=lane>>5 -> col half.
// Each lane holds W3[h][o][ch*64..+64) = 64 VGPRs. Inner loop = pure
// v_fma(w3_reg, x1_broadcast_from_LDS, acc): 1 FMA per MAC.
// W2 folds: contrib = x2[o]*(p + 0.5*W2[o]) summed over both col-halves.
// W1 folds: each lane does 2 FMAs on cols (ch*64+2*ol, +1), W1 prescaled 0.25
// (4 waves/head each cover the full row once).
// Head groups: blockIdx.y in {0,1} covers heads 4hg..4hg+3 (contiguous 2KB
// slice of each 4KB input row -> coalesced staging). Partials -> d_ws,
// tiny reduce kernel adds hg0+hg1+sum(b1).

#define NB 16384
#define NHEAD 8
#define NDIM 128
#define HPB 4            // heads per block
#define SCHUNK 8         // samples per LDS chunk
#define NCHUNK 16
#define SPB (SCHUNK * NCHUNK)   // 128 samples per block

__global__ __launch_bounds__(1024, 4) void bilinear_main(
    const float* __restrict__ x1, const float* __restrict__ x2,
    const float* __restrict__ W1, const float* __restrict__ W2,
    const float* __restrict__ W3, float* __restrict__ ws)
{
    const int tid = threadIdx.x;
    const int w   = tid >> 6;
    const int lane = tid & 63;
    const int h_local = w >> 2;
    const int q   = w & 3;
    const int ol  = lane & 31;
    const int ch  = lane >> 5;
    const int o   = q * 32 + ol;
    const int hg  = blockIdx.y;
    const int h   = hg * HPB + h_local;
    const int b0  = blockIdx.x * SPB;

    // ---- W3 into registers: lane holds W3[h][o][ch*64 .. +64) ----
    float w3r[64];
    {
        const float4* wp = reinterpret_cast<const float4*>(
            W3 + ((size_t)h * NDIM + o) * NDIM + ch * 64);
#pragma unroll
        for (int c = 0; c < 16; ++c) {
            const float4 v = wp[c];
            w3r[4*c+0] = v.x; w3r[4*c+1] = v.y;
            w3r[4*c+2] = v.z; w3r[4*c+3] = v.w;
        }
    }
    const float w2half = 0.5f  * W2[h * NDIM + o];
    const float w1a    = 0.25f * W1[h * NDIM + ch * 64 + 2 * ol];
    const float w1b    = 0.25f * W1[h * NDIM + ch * 64 + 2 * ol + 1];

    __shared__ float xs1[2][SCHUNK][HPB * NDIM];   // 16 KB x 2
    __shared__ float xs2[2][SCHUNK][HPB * NDIM];   // 16 KB x 2
    __shared__ float pw[16][SCHUNK];               // per-wave per-sample partials

    // ---- staging: 2 float4 loads per thread per chunk ----
    float4 v0, v1;
    auto load_chunk = [&](int chunk) {
#pragma unroll
        for (int k = 0; k < 2; ++k) {
            const int idx    = k * 1024 + tid;
            const int tensor = idx >> 10;          // 0 -> x1, 1 -> x2
            const int rem    = idx & 1023;
            const int s      = rem >> 7;
            const int f4     = rem & 127;
            const float* src = (tensor == 0 ? x1 : x2)
                + (size_t)(b0 + chunk * SCHUNK + s) * (NHEAD * NDIM)
                + hg * (HPB * NDIM) + f4 * 4;
            const float4 v = *reinterpret_cast<const float4*>(src);
            if (k == 0) v0 = v; else v1 = v;
        }
    };
    auto write_chunk = [&](int buf) {
#pragma unroll
        for (int k = 0; k < 2; ++k) {
            const int idx    = k * 1024 + tid;
            const int tensor = idx >> 10;
            const int rem    = idx & 1023;
            const int s      = rem >> 7;
            const int f4     = rem & 127;
            float* dst = (tensor == 0 ? &xs1[buf][s][0] : &xs2[buf][s][0]);
            reinterpret_cast<float4*>(dst)[f4] = (k == 0 ? v0 : v1);
        }
    };

    load_chunk(0);
    write_chunk(0);
    __syncthreads();

    for (int chunk = 0; chunk < NCHUNK; ++chunk) {
        const int cur = chunk & 1;
        if (chunk + 1 < NCHUNK) load_chunk(chunk + 1);   // issue early

        const int xoff = h_local * NDIM;
#pragma unroll
        for (int s = 0; s < SCHUNK; ++s) {
            const float* xb = &xs1[cur][s][xoff + ch * 64];
            float a0 = 0.f, a1 = 0.f, a2 = 0.f, a3 = 0.f;
#pragma unroll
            for (int c = 0; c < 16; ++c) {
                const float4 v = reinterpret_cast<const float4*>(xb)[c];
                a0 += w3r[4*c+0] * v.x;
                a1 += w3r[4*c+1] * v.y;
                a2 += w3r[4*c+2] * v.z;
                a3 += w3r[4*c+3] * v.w;
            }
            const float p   = (a0 + a1) + (a2 + a3);
            const float x2v = xs2[cur][s][xoff + o];
            const float2 xp = *reinterpret_cast<const float2*>(
                &xs1[cur][s][xoff + ch * 64 + 2 * ol]);
            float contrib = x2v * (p + w2half) + w1a * xp.x + w1b * xp.y;
#pragma unroll
            for (int m = 32; m >= 1; m >>= 1)
                contrib += __shfl_xor(contrib, m, 64);
            if (lane == 0) pw[w][s] = contrib;
        }
        __syncthreads();   // pw complete; xs[cur] reads done

        if (tid < SCHUNK) {   // 8 threads: sum 16 wave-partials, write ws
            float vsum = 0.f;
#pragma unroll
            for (int ww = 0; ww < 16; ++ww) vsum += pw[ww][tid];
            ws[(size_t)hg * NB + b0 + chunk * SCHUNK + tid] = vsum;
        }
        if (chunk + 1 < NCHUNK) write_chunk(cur ^ 1);
        __syncthreads();
    }
}

__global__ __launch_bounds__(256) void bilinear_reduce(
    const float* __restrict__ ws, const float* __restrict__ b1,
    float* __restrict__ out)
{
    const int i = blockIdx.x * 256 + threadIdx.x;
    float bs = 0.f;
#pragma unroll
    for (int hh = 0; hh < NHEAD; ++hh) bs += b1[hh];
    out[i] = ws[i] + ws[NB + i] + bs;
}

extern "C" void kernel_launch(void* const* d_in, const int* in_sizes, int n_in,
                              void* d_out, int out_size, void* d_ws, size_t ws_size,
                              hipStream_t stream) {
    const float* x1 = (const float*)d_in[0];
    const float* x2 = (const float*)d_in[1];
    const float* W1 = (const float*)d_in[2];
    const float* b1 = (const float*)d_in[3];
    const float* W2 = (const float*)d_in[4];
    const float* W3 = (const float*)d_in[5];
    float* out = (float*)d_out;
    float* ws  = (float*)d_ws;   // 2 * 16384 floats = 128 KB

    dim3 grid(NB / SPB, 2);      // 128 sample tiles x 2 head groups = 256 blocks
    bilinear_main<<<grid, dim3(1024), 0, stream>>>(x1, x2, W1, W2, W3, ws);
    bilinear_reduce<<<dim3(NB / 256), dim3(256), 0, stream>>>(ws, b1, out);
}

// Round 3
// 89.029 us; speedup vs baseline: 1.9867x; 1.3894x over previous
//
#include <hip/hip_runtime.h>

// out[b] = sum_h [ dot(x1_bh,W1_h) + b1_h + dot(x2_bh,W2_h)
//                  + sum_o x2_bh[o] * dot(W3_h[o,:], x1_bh) ]
// B=16384, HEAD=8, DIM=128.
//
// MFMA path: per head, P[b,o] = sum_i x1[b,i]*W3[h,o,i] via
// mfma_f32_16x16x32_bf16 with split-bf16 (x=hi+lo, w=hi+lo, 3 passes:
// hi*hi + lo*hi + hi*lo -> ~2^-16 relative error, fp32-comparable).
// Block = 512 thr = 8 waves; wave = head h, 64-sample tile (4 m-tiles).
// N=128 -> 8 n-tiles. acc[4][8] f32x4 = 128 VGPRs. A and B fragments are
// loaded DIRECTLY from global (L2/L3-resident working set) and converted
// in-register: no LDS staging, no barriers in the main loop.
// Fragment layouts (guide-verified m89/m91):
//   A: m = lane&15, k = (lane>>4)*8 + j
//   B: n = lane&15, k = (lane>>4)*8 + j   (B[k][n] = W3[h][n][k])
//   C/D: col(n) = lane&15, row(m) = (lane>>4)*4 + reg
// Epilogue: t3+t2 = sum_o (P[b,o]+W2[h,o])*x2[b,h,o] with 16-lane shuffle
// reduce; t1 from the original fp32 x1 values (pre-conversion) vs fp32 W1.

#define NB 16384
#define NHEAD 8
#define NDIM 128

typedef __attribute__((ext_vector_type(8))) short bf16x8;
typedef __attribute__((ext_vector_type(4))) float f32x4;

// split 8 consecutive fp32 at p into bf16 hi/lo fragments (truncation split:
// hi = top16(x); lo = bf16(x - asfloat(top16 bits)); dropped terms ~2^-16*x)
__device__ __forceinline__ void split8(const float* __restrict__ p,
                                       bf16x8& hi, bf16x8& lo,
                                       float* __restrict__ xf) {
    const float4 a = *reinterpret_cast<const float4*>(p);
    const float4 b = *reinterpret_cast<const float4*>(p + 4);
    xf[0] = a.x; xf[1] = a.y; xf[2] = a.z; xf[3] = a.w;
    xf[4] = b.x; xf[5] = b.y; xf[6] = b.z; xf[7] = b.w;
#pragma unroll
    for (int j = 0; j < 8; ++j) {
        const unsigned u = __float_as_uint(xf[j]);
        hi[j] = (short)(u >> 16);
        const float hf = __uint_as_float(u & 0xffff0000u);
        lo[j] = (short)(__float_as_uint(xf[j] - hf) >> 16);
    }
}

__global__ __launch_bounds__(512, 2) void bilinear_mfma(
    const float* __restrict__ x1, const float* __restrict__ x2,
    const float* __restrict__ W1, const float* __restrict__ b1,
    const float* __restrict__ W2, const float* __restrict__ W3,
    float* __restrict__ out)
{
    const int tid = threadIdx.x;
    const int w   = tid >> 6;
    const int l   = tid & 63;
    const int h   = __builtin_amdgcn_readfirstlane(w);  // wave = head
    const int lm  = l & 15;    // A-row m / B-col n / C-col n
    const int lg  = l >> 4;    // k-group; C-row group
    const int b0  = blockIdx.x * 64;

    f32x4 acc[4][8];
#pragma unroll
    for (int mt = 0; mt < 4; ++mt)
#pragma unroll
        for (int nt = 0; nt < 8; ++nt) acc[mt][nt] = (f32x4)0.f;

    float t1p[4] = {0.f, 0.f, 0.f, 0.f};

    const float* __restrict__ w1base = W1 + h * NDIM;
    const float* __restrict__ w3base = W3 + (size_t)h * NDIM * NDIM;

#pragma unroll
    for (int kk = 0; kk < 4; ++kk) {
        const int k0 = kk * 32 + lg * 8;

        // W1 k-slice (fp32, reused across m-tiles)
        float w1f[8];
        {
            const float4 a = *reinterpret_cast<const float4*>(w1base + k0);
            const float4 b = *reinterpret_cast<const float4*>(w1base + k0 + 4);
            w1f[0] = a.x; w1f[1] = a.y; w1f[2] = a.z; w1f[3] = a.w;
            w1f[4] = b.x; w1f[5] = b.y; w1f[6] = b.z; w1f[7] = b.w;
        }

        // A fragments (x1) + t1 partial from exact fp32 values
        bf16x8 ahi[4], alo[4];
#pragma unroll
        for (int mt = 0; mt < 4; ++mt) {
            const float* xp = x1 + (size_t)(b0 + mt * 16 + lm) * (NHEAD * NDIM)
                               + h * NDIM + k0;
            float xf[8];
            split8(xp, ahi[mt], alo[mt], xf);
#pragma unroll
            for (int j = 0; j < 8; ++j) t1p[mt] += xf[j] * w1f[j];
        }

        // B fragments (W3) + MFMA: 3-pass split accumulation
#pragma unroll
        for (int nt = 0; nt < 8; ++nt) {
            const float* wp = w3base + (size_t)(nt * 16 + lm) * NDIM + k0;
            bf16x8 bhi, blo;
            float wf[8];
            split8(wp, bhi, blo, wf);
#pragma unroll
            for (int mt = 0; mt < 4; ++mt)
                acc[mt][nt] = __builtin_amdgcn_mfma_f32_16x16x32_bf16(
                    ahi[mt], bhi, acc[mt][nt], 0, 0, 0);
#pragma unroll
            for (int mt = 0; mt < 4; ++mt)
                acc[mt][nt] = __builtin_amdgcn_mfma_f32_16x16x32_bf16(
                    alo[mt], bhi, acc[mt][nt], 0, 0, 0);
#pragma unroll
            for (int mt = 0; mt < 4; ++mt)
                acc[mt][nt] = __builtin_amdgcn_mfma_f32_16x16x32_bf16(
                    ahi[mt], blo, acc[mt][nt], 0, 0, 0);
        }
    }

    // ---- epilogue: contrib[b] = sum_o (P[b,o]+W2[h,o])*x2[b,h,o]; + t1 ----
    __shared__ float pw[NHEAD][64];
    __shared__ float pt[NHEAD][64];

    float w2v[8];
#pragma unroll
    for (int nt = 0; nt < 8; ++nt) w2v[nt] = W2[h * NDIM + nt * 16 + lm];

#pragma unroll
    for (int mt = 0; mt < 4; ++mt) {
        float cr[4];
#pragma unroll
        for (int r = 0; r < 4; ++r) {
            const float* x2p = x2
                + (size_t)(b0 + mt * 16 + lg * 4 + r) * (NHEAD * NDIM)
                + h * NDIM + lm;
            float s = 0.f;
#pragma unroll
            for (int nt = 0; nt < 8; ++nt)
                s += (acc[mt][nt][r] + w2v[nt]) * x2p[nt * 16];
            cr[r] = s;
        }
        // reduce over the 16 lanes of lm (covers all 128 o)
#pragma unroll
        for (int m = 1; m < 16; m <<= 1)
#pragma unroll
            for (int r = 0; r < 4; ++r) cr[r] += __shfl_xor(cr[r], m, 64);
        if (lm == 0)
#pragma unroll
            for (int r = 0; r < 4; ++r) pw[w][mt * 16 + lg * 4 + r] = cr[r];

        // t1: in-lane k-sum done; reduce across the 4 lg groups
        float t = t1p[mt];
        t += __shfl_xor(t, 16, 64);
        t += __shfl_xor(t, 32, 64);
        if (l < 16) pt[w][mt * 16 + l] = t;
    }
    __syncthreads();

    if (w == 0) {
        float s = 0.f;
#pragma unroll
        for (int hh = 0; hh < NHEAD; ++hh)
            s += pw[hh][l] + pt[hh][l] + b1[hh];
        out[b0 + l] = s;
    }
}

extern "C" void kernel_launch(void* const* d_in, const int* in_sizes, int n_in,
                              void* d_out, int out_size, void* d_ws, size_t ws_size,
                              hipStream_t stream) {
    const float* x1 = (const float*)d_in[0];
    const float* x2 = (const float*)d_in[1];
    const float* W1 = (const float*)d_in[2];
    const float* b1 = (const float*)d_in[3];
    const float* W2 = (const float*)d_in[4];
    const float* W3 = (const float*)d_in[5];
    float* out = (float*)d_out;

    bilinear_mfma<<<dim3(NB / 64), dim3(512), 0, stream>>>(
        x1, x2, W1, b1, W2, W3, out);
}